// Round 13
// baseline (321.571 us; speedup 1.0000x reference)
//
#include <hip/hip_runtime.h>
#include <hip/hip_bf16.h>
#include <cstddef>

#define NN 50000
#define EE 800000
#define TE 850000   // EE + NN self loops
#define INC 256
#define C1 128      // heads(2) * hid(64)
#define C2 64
#define NCHUNK 49   // ceil(NN/1024)

// block-range dispatch for merged kernels
#define NB_COUNT 3321   // ceil(TE/256)
#define NB_CAST  12500  // NN*INC elements / 4 per thread / 256 threads
#define NB_P1    256
#define NB_P2    128
#define NB_K1    (NB_COUNT + NB_CAST + NB_P1 + NB_P2)
#define NB_GEMM1 782    // 391*2 (128x128 tiles over 50000x256)
#define NB_K2    (NB_COUNT + NB_GEMM1)

#define LOG2E 1.44269504088896340736f

typedef unsigned short ushort_t;
typedef short bf16x8 __attribute__((ext_vector_type(8)));
typedef float f32x4 __attribute__((ext_vector_type(4)));

__device__ inline ushort_t bf16r(float f) {  // RNE float->bf16
    unsigned u = __float_as_uint(f);
    unsigned r = (u + 0x7fffu + ((u >> 16) & 1u)) >> 16;
    return (ushort_t)r;
}
#define LOF(u) (__uint_as_float((u) << 16))           // low bf16 of packed uint
#define HIF(u) (__uint_as_float((u) & 0xffff0000u))   // high bf16 of packed uint
#define ELU(t) ((t) > 0.f ? (t) : (__expf(t) - 1.f))

__device__ inline void unpack8(uint4 u, float* f) {
    f[0] = LOF(u.x); f[1] = HIF(u.x); f[2] = LOF(u.y); f[3] = HIF(u.y);
    f[4] = LOF(u.z); f[5] = HIF(u.z); f[6] = LOF(u.w); f[7] = HIF(u.w);
}

// ---------------- scans (serial dependency, small) ----------------

__global__ void k_scan1(const int* __restrict__ deg, int* __restrict__ incl,
                        int* __restrict__ totals) {
    __shared__ int lds[1024];
    int t = threadIdx.x;
    int i = blockIdx.x * 1024 + t;
    int v = (i < NN) ? deg[i] : 0;
    lds[t] = v;
    __syncthreads();
    for (int off = 1; off < 1024; off <<= 1) {
        int add = (t >= off) ? lds[t - off] : 0;
        __syncthreads();
        lds[t] += add;
        __syncthreads();
    }
    if (i < NN) incl[i] = lds[t];
    if (t == 1023) totals[blockIdx.x] = lds[t];
}

// scan3 with inline chunk-offset (scan2 folded in; chunk = blockIdx.x>>2 is uniform)
__global__ void k_scan3(const int* __restrict__ incl, const int* __restrict__ deg,
                        const int* __restrict__ totals, int* __restrict__ rowstart) {
    int i = blockIdx.x * blockDim.x + threadIdx.x;
    if (i == 0) rowstart[NN] = TE;
    if (i >= NN) return;
    int chunk = blockIdx.x >> 2;
    int coff = 0;
    for (int c = 0; c < chunk; c++) coff += totals[c];
    rowstart[i] = incl[i] - deg[i] + coff;
}

// ---------------- K1: count+rank | cast | prep_w1 | prep_w2 ----------------

__global__ __launch_bounds__(256) void k_stage1(
    const int* __restrict__ ei, int* __restrict__ deg, int* __restrict__ rank,
    const float* __restrict__ x, ushort_t* __restrict__ xb,
    const float* __restrict__ W1l, const float* __restrict__ W1r,
    const float* __restrict__ b1l, const float* __restrict__ b1r,
    ushort_t* __restrict__ Wt1, float* __restrict__ biasf1,
    const float* __restrict__ W2l, const float* __restrict__ W2r,
    const float* __restrict__ b2l, const float* __restrict__ b2r,
    ushort_t* __restrict__ Wt2, float* __restrict__ biasf2) {
    int b = blockIdx.x;
    int tid = threadIdx.x;
    if (b < NB_COUNT) {
        int e = b * 256 + tid;
        if (e < TE) {
            int dst = (e < EE) ? ei[EE + e] : (e - EE);
            rank[e] = atomicAdd(&deg[dst], 1);
        }
    } else if (b < NB_COUNT + NB_CAST) {
        int i = (b - NB_COUNT) * 256 + tid;  // < 3,200,000 float4's
        float4 a = ((const float4*)x)[i];
        ushort4 o;
        o.x = bf16r(a.x); o.y = bf16r(a.y); o.z = bf16r(a.z); o.w = bf16r(a.w);
        ((ushort4*)xb)[i] = o;
    } else if (b < NB_COUNT + NB_CAST + NB_P1) {
        int n = b - NB_COUNT - NB_CAST;
        int k = tid;
        const float* W = (n < 128) ? W1l : W1r;
        int c = (n < 128) ? n : n - 128;
        Wt1[(size_t)n * 256 + k] = bf16r(W[(size_t)k * 128 + c]);
        if (n == 0) biasf1[k] = (k < 128) ? b1l[k] : b1r[k - 128];
    } else {
        int n = b - NB_COUNT - NB_CAST - NB_P1;
        int k = tid;
        if (k < 128) {
            const float* W = (n < 64) ? W2l : W2r;
            int c = (n < 64) ? n : n - 64;
            Wt2[(size_t)n * 128 + k] = bf16r(W[(size_t)k * 64 + c]);
            if (n == 0) biasf2[k] = (k < 64) ? b2l[k] : b2r[k - 64];
        }
    }
}

// ---------------- bf16 MFMA GEMM body ----------------
// 128x128 tile, BK=32, 256 threads, 16x16x32 MFMA; LDS rows padded to 40 bf16.

template <int K, int NCOL>
__device__ inline void gemm_body(const ushort_t* __restrict__ A,
                                 const ushort_t* __restrict__ Bt,
                                 const float* __restrict__ bias,
                                 ushort_t* __restrict__ C, int M,
                                 int bm, int bn, ushort_t* As, ushort_t* Bs) {
    int tid = threadIdx.x;
    int w = tid >> 6, l = tid & 63;
    int wm = (w & 1) * 64, wn = (w >> 1) * 64;
    int lm = l & 15, half = l >> 4;

    f32x4 zero = {0.f, 0.f, 0.f, 0.f};
    f32x4 acc[4][4];
#pragma unroll
    for (int a = 0; a < 4; a++)
#pragma unroll
        for (int b = 0; b < 4; b++) acc[a][b] = zero;

    for (int k0 = 0; k0 < K; k0 += 32) {
#pragma unroll
        for (int q = 0; q < 2; q++) {
            int seg = q * 256 + tid;
            int m = seg >> 2;
            int ko = (seg & 3) * 8;
            *(float4*)&As[m * 40 + ko] = *(const float4*)&A[(size_t)(bm + m) * K + k0 + ko];
            *(float4*)&Bs[m * 40 + ko] = *(const float4*)&Bt[(size_t)(bn + m) * K + k0 + ko];
        }
        __syncthreads();
        bf16x8 af[4], bfr[4];
#pragma unroll
        for (int mi = 0; mi < 4; mi++)
            af[mi] = *(const bf16x8*)&As[(wm + mi * 16 + lm) * 40 + half * 8];
#pragma unroll
        for (int ni = 0; ni < 4; ni++)
            bfr[ni] = *(const bf16x8*)&Bs[(wn + ni * 16 + lm) * 40 + half * 8];
#pragma unroll
        for (int mi = 0; mi < 4; mi++)
#pragma unroll
            for (int ni = 0; ni < 4; ni++)
                acc[mi][ni] = __builtin_amdgcn_mfma_f32_16x16x32_bf16(
                    af[mi], bfr[ni], acc[mi][ni], 0, 0, 0);
        __syncthreads();
    }
#pragma unroll
    for (int ni = 0; ni < 4; ni++) {
        int col = bn + wn + ni * 16 + lm;
        float bv = bias[col];
#pragma unroll
        for (int mi = 0; mi < 4; mi++) {
            int rbase = bm + wm + mi * 16 + half * 4;
#pragma unroll
            for (int r = 0; r < 4; r++) {
                int row = rbase + r;
                if (row < M) C[(size_t)row * NCOL + col] = bf16r(acc[mi][ni][r] + bv);
            }
        }
    }
}

// ---------------- K2: scatter | GEMM layer-1 (scatter blocks FIRST) ----------------
// Scatter is latency-bound and short per block: start it immediately; GEMM
// compute blocks fill the machine while scatter's random stores drain.

__global__ __launch_bounds__(256) void k_gemm1_scatter(
    const ushort_t* __restrict__ A, const ushort_t* __restrict__ Bt,
    const float* __restrict__ bias, ushort_t* __restrict__ C,
    const int* __restrict__ ei, const int* __restrict__ rank,
    const int* __restrict__ rowstart, int* __restrict__ ssrc) {
    __shared__ __align__(16) ushort_t As[128 * 40];
    __shared__ __align__(16) ushort_t Bs[128 * 40];
    int b = blockIdx.x;
    if (b < NB_COUNT) {
        // atomic-free scatter: one independent 4B random store per edge
        int e = b * 256 + threadIdx.x;
        if (e < TE) {
            int s, d;
            if (e < EE) { s = ei[e]; d = ei[EE + e]; }
            else        { s = e - EE; d = s; }
            ssrc[rowstart[d] + rank[e]] = s;
        }
    } else {
        int g = b - NB_COUNT;
        int bm = (g >> 1) * 128;
        int bn = (g & 1) * 128;
        gemm_body<256, 256>(A, Bt, bias, C, NN, bm, bn, As, Bs);
    }
}

__global__ __launch_bounds__(256) void k_gemm2(
    const ushort_t* __restrict__ A, const ushort_t* __restrict__ Bt,
    const float* __restrict__ bias, ushort_t* __restrict__ C) {
    __shared__ __align__(16) ushort_t As[128 * 40];
    __shared__ __align__(16) ushort_t Bs[128 * 40];
    int bm = blockIdx.x * 128;
    gemm_body<128, 128>(A, Bt, bias, C, NN, bm, 0, As, Bs);
}

// ---------------- Fused GATv2 layer ----------------
// Layer 1: one wave/node; lane covers 8 channels (c1=lane&15 -> ch 8c1..8c1+7,
// head=c1>>3); edge slot es=lane>>4 (4 edges in flight). uint4 = 16B gathers.
// Butterfly xor{1,2,4} sums each head's 8-lane group. att pre-scaled by log2e,
// lrelu folded: att*lrelu(t) = (0.6att)t + (0.4att)|t|.

__global__ __launch_bounds__(256) void k_fused1(
    const ushort_t* __restrict__ xlr, const int* __restrict__ rowstart,
    const int* __restrict__ ssrc, const float* __restrict__ att,
    const float* __restrict__ bias,
    const float* __restrict__ g, const float* __restrict__ b,
    const float* __restrict__ m, const float* __restrict__ v,
    ushort_t* __restrict__ out) {
    int lane = threadIdx.x & 63;
    int i = blockIdx.x * 4 + (threadIdx.x >> 6);
    if (i >= NN) return;
    int es = lane >> 4;   // edge slot 0..3
    int c1 = lane & 15;   // channel group
    uint4 xru = *(const uint4*)&xlr[(size_t)i * 256 + 128 + 8 * c1];
    float xr[8];
    unpack8(xru, xr);
    float a6[8], a4[8];
    {
        float4 ta = *(const float4*)&att[8 * c1];
        float4 tb = *(const float4*)&att[8 * c1 + 4];
        float atv[8] = {ta.x, ta.y, ta.z, ta.w, tb.x, tb.y, tb.z, tb.w};
#pragma unroll
        for (int c = 0; c < 8; c++) {
            a6[c] = atv[c] * (0.6f * LOG2E);
            a4[c] = atv[c] * (0.4f * LOG2E);
        }
    }
    int row = rowstart[i], end = rowstart[i + 1];
    float acc[8] = {};
    float s = 0.f;
    int j = row;
    for (; j + 8 <= end; j += 8) {
        int s0 = ssrc[j + es], s1 = ssrc[j + 4 + es];
        uint4 u0 = *(const uint4*)&xlr[(size_t)s0 * 256 + 8 * c1];
        uint4 u1 = *(const uint4*)&xlr[(size_t)s1 * 256 + 8 * c1];
        float f0[8], f1[8];
        unpack8(u0, f0);
        unpack8(u1, f1);
        float d0 = 0.f, d1 = 0.f;
#pragma unroll
        for (int c = 0; c < 8; c++) {
            float t0 = f0[c] + xr[c];
            float t1 = f1[c] + xr[c];
            d0 = fmaf(a6[c], t0, fmaf(a4[c], fabsf(t0), d0));
            d1 = fmaf(a6[c], t1, fmaf(a4[c], fabsf(t1), d1));
        }
        d0 += __shfl_xor(d0, 1, 64); d1 += __shfl_xor(d1, 1, 64);
        d0 += __shfl_xor(d0, 2, 64); d1 += __shfl_xor(d1, 2, 64);
        d0 += __shfl_xor(d0, 4, 64); d1 += __shfl_xor(d1, 4, 64);
        float p0 = exp2f(d0), p1 = exp2f(d1);
#pragma unroll
        for (int c = 0; c < 8; c++) acc[c] = fmaf(p0, f0[c], fmaf(p1, f1[c], acc[c]));
        s += p0 + p1;
    }
    for (; j < end; j += 4) {
        int je = j + es;
        bool valid = je < end;
        int src = valid ? ssrc[je] : i;
        uint4 uu = *(const uint4*)&xlr[(size_t)src * 256 + 8 * c1];
        float f[8];
        unpack8(uu, f);
        float d = 0.f;
#pragma unroll
        for (int c = 0; c < 8; c++) {
            float t = f[c] + xr[c];
            d = fmaf(a6[c], t, fmaf(a4[c], fabsf(t), d));
        }
        d += __shfl_xor(d, 1, 64);
        d += __shfl_xor(d, 2, 64);
        d += __shfl_xor(d, 4, 64);
        float p = valid ? exp2f(d) : 0.f;
#pragma unroll
        for (int c = 0; c < 8; c++) acc[c] = fmaf(p, f[c], acc[c]);
        s += p;
    }
    // combine the 4 edge slots (channels replicated across es)
#pragma unroll
    for (int c = 0; c < 8; c++) {
        acc[c] += __shfl_xor(acc[c], 16, 64);
        acc[c] += __shfl_xor(acc[c], 32, 64);
    }
    s += __shfl_xor(s, 16, 64);
    s += __shfl_xor(s, 32, 64);
    if (es == 0) {
        float inv = 1.f / s;
        float4 bb0 = *(const float4*)&bias[8 * c1], bb1 = *(const float4*)&bias[8 * c1 + 4];
        float4 mm0 = *(const float4*)&m[8 * c1],   mm1 = *(const float4*)&m[8 * c1 + 4];
        float4 vv0 = *(const float4*)&v[8 * c1],   vv1 = *(const float4*)&v[8 * c1 + 4];
        float4 gg0 = *(const float4*)&g[8 * c1],   gg1 = *(const float4*)&g[8 * c1 + 4];
        float4 be0 = *(const float4*)&b[8 * c1],   be1 = *(const float4*)&b[8 * c1 + 4];
        float bbv[8] = {bb0.x, bb0.y, bb0.z, bb0.w, bb1.x, bb1.y, bb1.z, bb1.w};
        float mmv[8] = {mm0.x, mm0.y, mm0.z, mm0.w, mm1.x, mm1.y, mm1.z, mm1.w};
        float vvv[8] = {vv0.x, vv0.y, vv0.z, vv0.w, vv1.x, vv1.y, vv1.z, vv1.w};
        float ggv[8] = {gg0.x, gg0.y, gg0.z, gg0.w, gg1.x, gg1.y, gg1.z, gg1.w};
        float bev[8] = {be0.x, be0.y, be0.z, be0.w, be1.x, be1.y, be1.z, be1.w};
        unsigned wp[4];
#pragma unroll
        for (int c = 0; c < 8; c += 2) {
            float o0 = acc[c] * inv + bbv[c];
            float o1 = acc[c + 1] * inv + bbv[c + 1];
            o0 = (o0 - mmv[c]) * rsqrtf(vvv[c] + 1e-5f) * ggv[c] + bev[c];
            o1 = (o1 - mmv[c + 1]) * rsqrtf(vvv[c + 1] + 1e-5f) * ggv[c + 1] + bev[c + 1];
            o0 = ELU(o0); o1 = ELU(o1);
            wp[c >> 1] = (unsigned)bf16r(o0) | ((unsigned)bf16r(o1) << 16);
        }
        uint4 w4 = make_uint4(wp[0], wp[1], wp[2], wp[3]);
        *(uint4*)&out[(size_t)i * C1 + 8 * c1] = w4;
    }
}

// Layer 2 + classifier: lane covers 8 of 64 channels (c=lane&7), edge slot
// es=lane>>3 (8 edges in flight). Butterfly xor{1,2,4} over the 8-lane group.
__global__ __launch_bounds__(256) void k_fused2(
    const ushort_t* __restrict__ xlr, const int* __restrict__ rowstart,
    const int* __restrict__ ssrc, const float* __restrict__ att,
    const float* __restrict__ bias,
    const float* __restrict__ g, const float* __restrict__ b,
    const float* __restrict__ m, const float* __restrict__ v,
    const float* __restrict__ Wc, const float* __restrict__ bc,
    float* __restrict__ out) {
    int lane = threadIdx.x & 63;
    int i = blockIdx.x * 4 + (threadIdx.x >> 6);
    if (i >= NN) return;
    int es = lane >> 3;   // edge slot 0..7
    int cc = lane & 7;    // channel group
    uint4 xru = *(const uint4*)&xlr[(size_t)i * 128 + 64 + 8 * cc];
    float xr[8];
    unpack8(xru, xr);
    float a6[8], a4[8];
    {
        float4 ta = *(const float4*)&att[8 * cc];
        float4 tb = *(const float4*)&att[8 * cc + 4];
        float atv[8] = {ta.x, ta.y, ta.z, ta.w, tb.x, tb.y, tb.z, tb.w};
#pragma unroll
        for (int c = 0; c < 8; c++) {
            a6[c] = atv[c] * (0.6f * LOG2E);
            a4[c] = atv[c] * (0.4f * LOG2E);
        }
    }
    int row = rowstart[i], end = rowstart[i + 1];
    float acc[8] = {};
    float s = 0.f;
    int j = row;
    for (; j + 16 <= end; j += 16) {
        int s0 = ssrc[j + es], s1 = ssrc[j + 8 + es];
        uint4 u0 = *(const uint4*)&xlr[(size_t)s0 * 128 + 8 * cc];
        uint4 u1 = *(const uint4*)&xlr[(size_t)s1 * 128 + 8 * cc];
        float f0[8], f1[8];
        unpack8(u0, f0);
        unpack8(u1, f1);
        float d0 = 0.f, d1 = 0.f;
#pragma unroll
        for (int c = 0; c < 8; c++) {
            float t0 = f0[c] + xr[c];
            float t1 = f1[c] + xr[c];
            d0 = fmaf(a6[c], t0, fmaf(a4[c], fabsf(t0), d0));
            d1 = fmaf(a6[c], t1, fmaf(a4[c], fabsf(t1), d1));
        }
        d0 += __shfl_xor(d0, 1, 64); d1 += __shfl_xor(d1, 1, 64);
        d0 += __shfl_xor(d0, 2, 64); d1 += __shfl_xor(d1, 2, 64);
        d0 += __shfl_xor(d0, 4, 64); d1 += __shfl_xor(d1, 4, 64);
        float p0 = exp2f(d0), p1 = exp2f(d1);
#pragma unroll
        for (int c = 0; c < 8; c++) acc[c] = fmaf(p0, f0[c], fmaf(p1, f1[c], acc[c]));
        s += p0 + p1;
    }
    for (; j < end; j += 8) {
        int je = j + es;
        bool valid = je < end;
        int src = valid ? ssrc[je] : i;
        uint4 uu = *(const uint4*)&xlr[(size_t)src * 128 + 8 * cc];
        float f[8];
        unpack8(uu, f);
        float d = 0.f;
#pragma unroll
        for (int c = 0; c < 8; c++) {
            float t = f[c] + xr[c];
            d = fmaf(a6[c], t, fmaf(a4[c], fabsf(t), d));
        }
        d += __shfl_xor(d, 1, 64);
        d += __shfl_xor(d, 2, 64);
        d += __shfl_xor(d, 4, 64);
        float p = valid ? exp2f(d) : 0.f;
#pragma unroll
        for (int c = 0; c < 8; c++) acc[c] = fmaf(p, f[c], acc[c]);
        s += p;
    }
    // combine the 8 edge slots
#pragma unroll
    for (int c = 0; c < 8; c++) {
        acc[c] += __shfl_xor(acc[c], 8, 64);
        acc[c] += __shfl_xor(acc[c], 16, 64);
        acc[c] += __shfl_xor(acc[c], 32, 64);
    }
    s += __shfl_xor(s, 8, 64);
    s += __shfl_xor(s, 16, 64);
    s += __shfl_xor(s, 32, 64);
    if (es == 0) {
        float inv = 1.f / s;
        float4 bb0 = *(const float4*)&bias[8 * cc], bb1 = *(const float4*)&bias[8 * cc + 4];
        float4 mm0 = *(const float4*)&m[8 * cc],   mm1 = *(const float4*)&m[8 * cc + 4];
        float4 vv0 = *(const float4*)&v[8 * cc],   vv1 = *(const float4*)&v[8 * cc + 4];
        float4 gg0 = *(const float4*)&g[8 * cc],   gg1 = *(const float4*)&g[8 * cc + 4];
        float4 be0 = *(const float4*)&b[8 * cc],   be1 = *(const float4*)&b[8 * cc + 4];
        float4 wc0 = *(const float4*)&Wc[8 * cc],  wc1 = *(const float4*)&Wc[8 * cc + 4];
        float bbv[8] = {bb0.x, bb0.y, bb0.z, bb0.w, bb1.x, bb1.y, bb1.z, bb1.w};
        float mmv[8] = {mm0.x, mm0.y, mm0.z, mm0.w, mm1.x, mm1.y, mm1.z, mm1.w};
        float vvv[8] = {vv0.x, vv0.y, vv0.z, vv0.w, vv1.x, vv1.y, vv1.z, vv1.w};
        float ggv[8] = {gg0.x, gg0.y, gg0.z, gg0.w, gg1.x, gg1.y, gg1.z, gg1.w};
        float bev[8] = {be0.x, be0.y, be0.z, be0.w, be1.x, be1.y, be1.z, be1.w};
        float wcv[8] = {wc0.x, wc0.y, wc0.z, wc0.w, wc1.x, wc1.y, wc1.z, wc1.w};
        float z = 0.f;
#pragma unroll
        for (int c = 0; c < 8; c++) {
            float o = acc[c] * inv + bbv[c];
            o = (o - mmv[c]) * rsqrtf(vvv[c] + 1e-5f) * ggv[c] + bev[c];
            o = ELU(o);
            z = fmaf(o, wcv[c], z);
        }
        z += __shfl_xor(z, 1, 64);
        z += __shfl_xor(z, 2, 64);
        z += __shfl_xor(z, 4, 64);
        if (cc == 0) out[i] = 1.f / (1.f + __expf(-(z + bc[0])));
    }
}

// ---------------- launch ----------------

extern "C" void kernel_launch(void* const* d_in, const int* in_sizes, int n_in,
                              void* d_out, int out_size, void* d_ws, size_t ws_size,
                              hipStream_t stream) {
    const float* x    = (const float*)d_in[0];
    const int*   ei   = (const int*)d_in[1];
    const float* W1l  = (const float*)d_in[2];
    const float* b1l  = (const float*)d_in[3];
    const float* W1r  = (const float*)d_in[4];
    const float* b1r  = (const float*)d_in[5];
    const float* att1 = (const float*)d_in[6];
    const float* bias1= (const float*)d_in[7];
    const float* bn1g = (const float*)d_in[8];
    const float* bn1b = (const float*)d_in[9];
    const float* bn1m = (const float*)d_in[10];
    const float* bn1v = (const float*)d_in[11];
    const float* W2l  = (const float*)d_in[12];
    const float* b2l  = (const float*)d_in[13];
    const float* W2r  = (const float*)d_in[14];
    const float* b2r  = (const float*)d_in[15];
    const float* att2 = (const float*)d_in[16];
    const float* bias2= (const float*)d_in[17];
    const float* bn2g = (const float*)d_in[18];
    const float* bn2b = (const float*)d_in[19];
    const float* bn2m = (const float*)d_in[20];
    const float* bn2v = (const float*)d_in[21];
    const float* Wc   = (const float*)d_in[22];
    const float* bc   = (const float*)d_in[23];
    float* out = (float*)d_out;

    char* ws = (char*)d_ws;
    size_t off = 0;
    auto alloc = [&](size_t bytes) {
        size_t o = off;
        off += (bytes + 255) & ~(size_t)255;
        return o;
    };
    ushort_t* xb    = (ushort_t*)(ws + alloc((size_t)(NN + 128) * 256 * 2));
    ushort_t* xlr1  = (ushort_t*)(ws + alloc((size_t)NN * 256 * 2));  // reused as xlr2
    ushort_t* h1b   = (ushort_t*)(ws + alloc((size_t)(NN + 128) * 128 * 2));
    ushort_t* Wt1   = (ushort_t*)(ws + alloc((size_t)256 * 256 * 2));
    float*    biasf1= (float*)(ws + alloc(256 * 4));
    ushort_t* Wt2   = (ushort_t*)(ws + alloc((size_t)128 * 128 * 2));
    float*    biasf2= (float*)(ws + alloc(128 * 4));
    int* deg      = (int*)(ws + alloc((size_t)NN * 4));
    int* incl     = (int*)(ws + alloc((size_t)NN * 4));
    int* rowstart = (int*)(ws + alloc((size_t)(NN + 1) * 4));
    int* totals   = (int*)(ws + alloc(64 * 4));
    int* rank     = (int*)(ws + alloc((size_t)TE * 4));
    int* ssrc     = (int*)(ws + alloc((size_t)TE * 4));
    ushort_t* xlr2 = xlr1;

    // deg = 0
    hipMemsetAsync(deg, 0, (size_t)NN * 4, stream);

    // K1: count+rank | cast x->bf16 | prep W1 | prep W2 (all independent)
    k_stage1<<<NB_K1, 256, 0, stream>>>(ei, deg, rank, x, xb,
                                        W1l, W1r, b1l, b1r, Wt1, biasf1,
                                        W2l, W2r, b2l, b2r, Wt2, biasf2);

    // scans (serial, small; scan2 folded into scan3)
    k_scan1<<<NCHUNK, 1024, 0, stream>>>(deg, incl, totals);
    k_scan3<<<(NN + 255) / 256, 256, 0, stream>>>(incl, deg, totals, rowstart);

    // K2: scatter | GEMM layer-1 (scatter blocks first)
    k_gemm1_scatter<<<NB_K2, 256, 0, stream>>>(xb, Wt1, biasf1, xlr1,
                                               ei, rank, rowstart, ssrc);

    // layer 1 fused
    k_fused1<<<(NN + 3) / 4, 256, 0, stream>>>(xlr1, rowstart, ssrc, att1, bias1,
                                               bn1g, bn1b, bn1m, bn1v, h1b);

    // layer 2 (+classifier)
    k_gemm2<<<(NN + 127) / 128, 256, 0, stream>>>(h1b, Wt2, biasf2, xlr2);
    k_fused2<<<(NN + 3) / 4, 256, 0, stream>>>(xlr2, rowstart, ssrc, att2, bias2,
                                               bn2g, bn2b, bn2m, bn2v, Wc, bc, out);
}